// Round 1
// baseline (10637.214 us; speedup 1.0000x reference)
//
#include <hip/hip_runtime.h>
#include <math.h>

#define N_NODES 50000
#define N_EDGES 800000
#define F 64
#define R 32
#define C3F 192   // 3*F

// ---------------------------------------------------------------------------
// Kernel 1: hidden = silu(s @ W1 + b1)            (N x 64)
// thread = (node, seg) ; seg handles 8 output features.
// s row held in 64 VGPRs (static unroll); W1 read as float4 (coalesced).
// ---------------------------------------------------------------------------
__global__ __launch_bounds__(256) void hidden_kernel(
    const float* __restrict__ s, const float* __restrict__ W1,
    const float* __restrict__ b1, float* __restrict__ hid)
{
    int tid = blockIdx.x * 256 + threadIdx.x;
    int n = tid >> 3;
    int seg = tid & 7;          // 8 segs * 8 feats = 64
    if (n >= N_NODES) return;

    float sv[F];
    const float4* srow = (const float4*)(s + (size_t)n * F);
#pragma unroll
    for (int q = 0; q < F / 4; q++) {
        float4 t = srow[q];
        sv[4*q+0] = t.x; sv[4*q+1] = t.y; sv[4*q+2] = t.z; sv[4*q+3] = t.w;
    }

    float acc[8];
#pragma unroll
    for (int q = 0; q < 8; q++) acc[q] = b1[seg * 8 + q];

#pragma unroll
    for (int k = 0; k < F; k++) {
        float sk = sv[k];
        const float4* w = (const float4*)(W1 + (size_t)k * F + seg * 8);
        float4 w0 = w[0], w1 = w[1];
        acc[0] += sk * w0.x; acc[1] += sk * w0.y;
        acc[2] += sk * w0.z; acc[3] += sk * w0.w;
        acc[4] += sk * w1.x; acc[5] += sk * w1.y;
        acc[6] += sk * w1.z; acc[7] += sk * w1.w;
    }

#pragma unroll
    for (int q = 0; q < 8; q++) {
        float a = acc[q];
        acc[q] = a / (1.f + __expf(-a));   // silu; correct limits at +/-inf
    }

    float4* o = (float4*)(hid + (size_t)n * F + seg * 8);
    o[0] = make_float4(acc[0], acc[1], acc[2], acc[3]);
    o[1] = make_float4(acc[4], acc[5], acc[6], acc[7]);
}

// ---------------------------------------------------------------------------
// Kernel 2: phi = hidden @ W2 + b2                (N x 192)
// thread = (node, seg) ; seg handles 24 output features.
// ---------------------------------------------------------------------------
__global__ __launch_bounds__(256) void phi_kernel(
    const float* __restrict__ hid, const float* __restrict__ W2,
    const float* __restrict__ b2, float* __restrict__ phi)
{
    int tid = blockIdx.x * 256 + threadIdx.x;
    int n = tid >> 3;
    int seg = tid & 7;          // 8 segs * 24 feats = 192
    if (n >= N_NODES) return;

    float hv[F];
    const float4* hrow = (const float4*)(hid + (size_t)n * F);
#pragma unroll
    for (int q = 0; q < F / 4; q++) {
        float4 t = hrow[q];
        hv[4*q+0] = t.x; hv[4*q+1] = t.y; hv[4*q+2] = t.z; hv[4*q+3] = t.w;
    }

    float acc[24];
#pragma unroll
    for (int q = 0; q < 24; q++) acc[q] = b2[seg * 24 + q];

#pragma unroll
    for (int k = 0; k < F; k++) {
        float hk = hv[k];
        const float4* w = (const float4*)(W2 + (size_t)k * C3F + seg * 24);
#pragma unroll
        for (int q4 = 0; q4 < 6; q4++) {
            float4 wv = w[q4];
            acc[q4*4+0] += hk * wv.x;
            acc[q4*4+1] += hk * wv.y;
            acc[q4*4+2] += hk * wv.z;
            acc[q4*4+3] += hk * wv.w;
        }
    }

    float4* o = (float4*)(phi + (size_t)n * C3F + seg * 24);
#pragma unroll
    for (int q4 = 0; q4 < 6; q4++)
        o[q4] = make_float4(acc[q4*4+0], acc[q4*4+1], acc[q4*4+2], acc[q4*4+3]);
}

// ---------------------------------------------------------------------------
// Kernel 3: per-edge filter + gather + scatter-add.
// thread = edge. radial row in 32 VGPRs; Wr/br accesses are wave-uniform
// (loop-counter indices) -> scalar loads -> FMA stream at issue rate.
// 8-feature chunks over the 64 feature dim; 3 columns (s, vv, vs) at once.
// ---------------------------------------------------------------------------
__global__ __launch_bounds__(256) void edge_kernel(
    const float* __restrict__ phi, const float* __restrict__ v,
    const float* __restrict__ radial, const float* __restrict__ f_cut,
    const float* __restrict__ unit_vec, const int* __restrict__ eidx,
    const float* __restrict__ Wr, const float* __restrict__ br,
    float* __restrict__ out_s, float* __restrict__ out_v)
{
    int e = blockIdx.x * 256 + threadIdx.x;
    if (e >= N_EDGES) return;

    int i = eidx[e];
    int j = eidx[N_EDGES + e];
    float fc = f_cut[e];
    float u0 = unit_vec[e * 3 + 0];
    float u1 = unit_vec[e * 3 + 1];
    float u2 = unit_vec[e * 3 + 2];

    float rad[R];
    const float4* rrow = (const float4*)(radial + (size_t)e * R);
#pragma unroll
    for (int q = 0; q < R / 4; q++) {
        float4 t = rrow[q];
        rad[4*q+0] = t.x; rad[4*q+1] = t.y; rad[4*q+2] = t.z; rad[4*q+3] = t.w;
    }

    const float* phij = phi + (size_t)j * C3F;
    const float* vj   = v   + (size_t)j * 3 * F;
    float* outsi = out_s + (size_t)i * F;
    float* outvi = out_v + (size_t)i * 3 * F;

    for (int fcnk = 0; fcnk < 8; fcnk++) {   // dynamic loop: keeps code size sane
        int f = fcnk * 8;

        float ws[8], wvv[8], wvs[8];
#pragma unroll
        for (int q = 0; q < 8; q++) {
            ws[q]  = br[f + q];
            wvv[q] = br[64 + f + q];
            wvs[q] = br[128 + f + q];
        }

#pragma unroll
        for (int r = 0; r < R; r++) {
            float rr = rad[r];
            const float* wr = Wr + (size_t)r * C3F + f;   // wave-uniform -> s_load
#pragma unroll
            for (int q = 0; q < 8; q++) {
                ws[q]  += rr * wr[q];
                wvv[q] += rr * wr[64 + q];
                wvs[q] += rr * wr[128 + q];
            }
        }

        // gather phi[j] chunks
        float4 p0 = *(const float4*)(phij + f);
        float4 p1 = *(const float4*)(phij + f + 4);
        float4 a0 = *(const float4*)(phij + 64 + f);
        float4 a1 = *(const float4*)(phij + 64 + f + 4);
        float4 c0 = *(const float4*)(phij + 128 + f);
        float4 c1 = *(const float4*)(phij + 128 + f + 4);
        float ps[8]  = {p0.x,p0.y,p0.z,p0.w,p1.x,p1.y,p1.z,p1.w};
        float pvv[8] = {a0.x,a0.y,a0.z,a0.w,a1.x,a1.y,a1.z,a1.w};
        float pvs[8] = {c0.x,c0.y,c0.z,c0.w,c1.x,c1.y,c1.z,c1.w};

        float xs[8], xvv[8], xvs[8];
#pragma unroll
        for (int q = 0; q < 8; q++) {
            xs[q]  = ps[q]  * ws[q]  * fc;
            xvv[q] = pvv[q] * wvv[q] * fc;
            xvs[q] = pvs[q] * wvs[q] * fc;
        }

#pragma unroll
        for (int q = 0; q < 8; q++)
            atomicAdd(&outsi[f + q], xs[q]);

#pragma unroll
        for (int d = 0; d < 3; d++) {
            float ud = (d == 0) ? u0 : ((d == 1) ? u1 : u2);
            float4 v0 = *(const float4*)(vj + d * F + f);
            float4 v1 = *(const float4*)(vj + d * F + f + 4);
            float vv[8] = {v0.x,v0.y,v0.z,v0.w,v1.x,v1.y,v1.z,v1.w};
#pragma unroll
            for (int q = 0; q < 8; q++)
                atomicAdd(&outvi[d * F + f + q], vv[q] * xvv[q] + xvs[q] * ud);
        }
    }
}

// ---------------------------------------------------------------------------
extern "C" void kernel_launch(void* const* d_in, const int* in_sizes, int n_in,
                              void* d_out, int out_size, void* d_ws, size_t ws_size,
                              hipStream_t stream)
{
    const float* s      = (const float*)d_in[0];
    const float* v      = (const float*)d_in[1];
    const float* radial = (const float*)d_in[2];
    const float* f_cut  = (const float*)d_in[3];
    const float* unit   = (const float*)d_in[4];
    const int*   eidx   = (const int*)  d_in[5];
    const float* W1     = (const float*)d_in[6];
    const float* b1     = (const float*)d_in[7];
    const float* W2     = (const float*)d_in[8];
    const float* b2     = (const float*)d_in[9];
    const float* Wr     = (const float*)d_in[10];
    const float* br     = (const float*)d_in[11];

    float* out   = (float*)d_out;
    float* phi   = (float*)d_ws;                       // N*192 floats
    float* hid   = phi + (size_t)N_NODES * C3F;        // N*64 floats
    float* out_s = out;
    float* out_v = out + (size_t)N_NODES * F;

    // out starts as (s, v); edge kernel accumulates ds/dv on top.
    hipMemcpyAsync(out_s, s, (size_t)N_NODES * F * sizeof(float),
                   hipMemcpyDeviceToDevice, stream);
    hipMemcpyAsync(out_v, v, (size_t)N_NODES * 3 * F * sizeof(float),
                   hipMemcpyDeviceToDevice, stream);

    int mlp_threads = N_NODES * 8;
    hidden_kernel<<<(mlp_threads + 255) / 256, 256, 0, stream>>>(s, W1, b1, hid);
    phi_kernel<<<(mlp_threads + 255) / 256, 256, 0, stream>>>(hid, W2, b2, phi);
    edge_kernel<<<(N_EDGES + 255) / 256, 256, 0, stream>>>(
        phi, v, radial, f_cut, unit, eidx, Wr, br, out_s, out_v);
}

// Round 2
// 1230.721 us; speedup vs baseline: 8.6431x; 8.6431x over previous
//
#include <hip/hip_runtime.h>
#include <math.h>

#define N_NODES 50000
#define N_EDGES 800000
#define F 64
#define R 32
#define C3F 192   // 3*F

// ---------------------------------------------------------------------------
// Kernel 1: hidden = silu(s @ W1 + b1)            (N x 64)
// ---------------------------------------------------------------------------
__global__ __launch_bounds__(256) void hidden_kernel(
    const float* __restrict__ s, const float* __restrict__ W1,
    const float* __restrict__ b1, float* __restrict__ hid)
{
    int tid = blockIdx.x * 256 + threadIdx.x;
    int n = tid >> 3;
    int seg = tid & 7;          // 8 segs * 8 feats = 64
    if (n >= N_NODES) return;

    float sv[F];
    const float4* srow = (const float4*)(s + (size_t)n * F);
#pragma unroll
    for (int q = 0; q < F / 4; q++) {
        float4 t = srow[q];
        sv[4*q+0] = t.x; sv[4*q+1] = t.y; sv[4*q+2] = t.z; sv[4*q+3] = t.w;
    }

    float acc[8];
#pragma unroll
    for (int q = 0; q < 8; q++) acc[q] = b1[seg * 8 + q];

#pragma unroll
    for (int k = 0; k < F; k++) {
        float sk = sv[k];
        const float4* w = (const float4*)(W1 + (size_t)k * F + seg * 8);
        float4 w0 = w[0], w1 = w[1];
        acc[0] += sk * w0.x; acc[1] += sk * w0.y;
        acc[2] += sk * w0.z; acc[3] += sk * w0.w;
        acc[4] += sk * w1.x; acc[5] += sk * w1.y;
        acc[6] += sk * w1.z; acc[7] += sk * w1.w;
    }

#pragma unroll
    for (int q = 0; q < 8; q++) {
        float a = acc[q];
        acc[q] = a / (1.f + __expf(-a));   // silu
    }

    float4* o = (float4*)(hid + (size_t)n * F + seg * 8);
    o[0] = make_float4(acc[0], acc[1], acc[2], acc[3]);
    o[1] = make_float4(acc[4], acc[5], acc[6], acc[7]);
}

// ---------------------------------------------------------------------------
// Kernel 2: phi = hidden @ W2 + b2                (N x 192)
// ---------------------------------------------------------------------------
__global__ __launch_bounds__(256) void phi_kernel(
    const float* __restrict__ hid, const float* __restrict__ W2,
    const float* __restrict__ b2, float* __restrict__ phi)
{
    int tid = blockIdx.x * 256 + threadIdx.x;
    int n = tid >> 3;
    int seg = tid & 7;          // 8 segs * 24 feats = 192
    if (n >= N_NODES) return;

    float hv[F];
    const float4* hrow = (const float4*)(hid + (size_t)n * F);
#pragma unroll
    for (int q = 0; q < F / 4; q++) {
        float4 t = hrow[q];
        hv[4*q+0] = t.x; hv[4*q+1] = t.y; hv[4*q+2] = t.z; hv[4*q+3] = t.w;
    }

    float acc[24];
#pragma unroll
    for (int q = 0; q < 24; q++) acc[q] = b2[seg * 24 + q];

#pragma unroll
    for (int k = 0; k < F; k++) {
        float hk = hv[k];
        const float4* w = (const float4*)(W2 + (size_t)k * C3F + seg * 24);
#pragma unroll
        for (int q4 = 0; q4 < 6; q4++) {
            float4 wv = w[q4];
            acc[q4*4+0] += hk * wv.x;
            acc[q4*4+1] += hk * wv.y;
            acc[q4*4+2] += hk * wv.z;
            acc[q4*4+3] += hk * wv.w;
        }
    }

    float4* o = (float4*)(phi + (size_t)n * C3F + seg * 24);
#pragma unroll
    for (int q4 = 0; q4 < 6; q4++)
        o[q4] = make_float4(acc[q4*4+0], acc[q4*4+1], acc[q4*4+2], acc[q4*4+3]);
}

// ---------------------------------------------------------------------------
// CSR build: histogram -> scan -> fill
// ---------------------------------------------------------------------------
__global__ __launch_bounds__(256) void hist_kernel(
    const int* __restrict__ eidx, int* __restrict__ counts)
{
    int e = blockIdx.x * 256 + threadIdx.x;
    if (e < N_EDGES) atomicAdd(&counts[eidx[e]], 1);
}

// single block of 1024: exclusive scan of counts[0..N_NODES) into offsets,
// plus a second copy into cursor (fill's bump allocator).
__global__ __launch_bounds__(1024) void scan_kernel(
    const int* __restrict__ counts, int* __restrict__ offsets,
    int* __restrict__ cursor)
{
    __shared__ int sdata[1024];
    int tid = threadIdx.x;
    const int chunk = (N_NODES + 1023) / 1024;   // 49
    int base = tid * chunk;

    int sum = 0;
    for (int q = 0; q < chunk; q++) {
        int idx = base + q;
        if (idx < N_NODES) sum += counts[idx];
    }
    sdata[tid] = sum;
    __syncthreads();
    for (int off = 1; off < 1024; off <<= 1) {   // Hillis-Steele inclusive scan
        int vv = (tid >= off) ? sdata[tid - off] : 0;
        __syncthreads();
        sdata[tid] += vv;
        __syncthreads();
    }
    int run = sdata[tid] - sum;                  // exclusive prefix for my chunk
    for (int q = 0; q < chunk; q++) {
        int idx = base + q;
        if (idx < N_NODES) {
            offsets[idx] = run;
            cursor[idx]  = run;
            run += counts[idx];
        }
    }
}

__global__ __launch_bounds__(256) void fill_kernel(
    const int* __restrict__ eidx, int* __restrict__ cursor,
    int* __restrict__ csr)
{
    int e = blockIdx.x * 256 + threadIdx.x;
    if (e < N_EDGES) {
        int pos = atomicAdd(&cursor[eidx[e]], 1);
        csr[pos] = e;
    }
}

// ---------------------------------------------------------------------------
// Gather kernel: one wave per node, lane l owns feature l of all 4 output
// columns (ds, dv0, dv1, dv2). Zero output atomics.
// Lane holds its 3 Wr columns in 96 VGPRs; radial row broadcast via __shfl.
// After fill_kernel, cursor[i] == row end.
// ---------------------------------------------------------------------------
__global__ __launch_bounds__(256) void gather_kernel(
    const float* __restrict__ s, const float* __restrict__ v,
    const float* __restrict__ phi, const float* __restrict__ radial,
    const float* __restrict__ f_cut, const float* __restrict__ unit_vec,
    const int* __restrict__ eidx, const float* __restrict__ Wr,
    const float* __restrict__ br, const int* __restrict__ offsets,
    const int* __restrict__ ends, const int* __restrict__ csr,
    float* __restrict__ out_s, float* __restrict__ out_v)
{
    int wave = threadIdx.x >> 6;
    int lane = threadIdx.x & 63;
    int node = blockIdx.x * 4 + wave;
    if (node >= N_NODES) return;

    // lane's 3 Wr columns (s, vv, vs) -> VGPRs. Wr is 24 KB, L1/L2-hot.
    float wr_s[R], wr_vv[R], wr_vs[R];
#pragma unroll
    for (int r = 0; r < R; r++) {
        const float* wrow = Wr + r * C3F;
        wr_s[r]  = wrow[lane];
        wr_vv[r] = wrow[64 + lane];
        wr_vs[r] = wrow[128 + lane];
    }
    float b_s = br[lane], b_vv = br[64 + lane], b_vs = br[128 + lane];

    float acc_s = 0.f, acc_v0 = 0.f, acc_v1 = 0.f, acc_v2 = 0.f;

    int k0 = offsets[node], k1 = ends[node];
    for (int k = k0; k < k1; k++) {
        int e = csr[k];
        int j = eidx[N_EDGES + e];
        float fc = f_cut[e];
        float u0 = unit_vec[e * 3 + 0];
        float u1 = unit_vec[e * 3 + 1];
        float u2 = unit_vec[e * 3 + 2];
        float rad_l = radial[(size_t)e * R + (lane & 31)];

        float ws = b_s, wvv = b_vv, wvs = b_vs;
#pragma unroll
        for (int r = 0; r < R; r++) {
            float rr = __shfl(rad_l, r);
            ws  += rr * wr_s[r];
            wvv += rr * wr_vv[r];
            wvs += rr * wr_vs[r];
        }

        const float* phij = phi + (size_t)j * C3F;
        float xs  = phij[lane]       * ws  * fc;
        float xvv = phij[64 + lane]  * wvv * fc;
        float xvs = phij[128 + lane] * wvs * fc;

        const float* vj = v + (size_t)j * C3F;
        acc_s  += xs;
        acc_v0 += vj[lane]       * xvv + xvs * u0;
        acc_v1 += vj[64 + lane]  * xvv + xvs * u1;
        acc_v2 += vj[128 + lane] * xvv + xvs * u2;
    }

    out_s[(size_t)node * F + lane] = s[(size_t)node * F + lane] + acc_s;
    const float* vi = v + (size_t)node * C3F;
    float* ovi = out_v + (size_t)node * C3F;
    ovi[lane]       = vi[lane]       + acc_v0;
    ovi[64 + lane]  = vi[64 + lane]  + acc_v1;
    ovi[128 + lane] = vi[128 + lane] + acc_v2;
}

// ---------------------------------------------------------------------------
extern "C" void kernel_launch(void* const* d_in, const int* in_sizes, int n_in,
                              void* d_out, int out_size, void* d_ws, size_t ws_size,
                              hipStream_t stream)
{
    const float* s      = (const float*)d_in[0];
    const float* v      = (const float*)d_in[1];
    const float* radial = (const float*)d_in[2];
    const float* f_cut  = (const float*)d_in[3];
    const float* unit   = (const float*)d_in[4];
    const int*   eidx   = (const int*)  d_in[5];
    const float* W1     = (const float*)d_in[6];
    const float* b1     = (const float*)d_in[7];
    const float* W2     = (const float*)d_in[8];
    const float* b2     = (const float*)d_in[9];
    const float* Wr     = (const float*)d_in[10];
    const float* br     = (const float*)d_in[11];

    float* out   = (float*)d_out;
    float* out_s = out;
    float* out_v = out + (size_t)N_NODES * F;

    // workspace layout
    float* phi     = (float*)d_ws;                         // 50000*192 f32
    float* hid     = phi + (size_t)N_NODES * C3F;          // 50000*64  f32
    int*   counts  = (int*)(hid + (size_t)N_NODES * F);    // 50000
    int*   offsets = counts + N_NODES;                     // 50000
    int*   cursor  = offsets + N_NODES;                    // 50000
    int*   csr     = cursor + N_NODES;                     // 800000
    // total ~55 MB

    hipMemsetAsync(counts, 0, N_NODES * sizeof(int), stream);

    int mlp_threads = N_NODES * 8;
    hidden_kernel<<<(mlp_threads + 255) / 256, 256, 0, stream>>>(s, W1, b1, hid);
    phi_kernel<<<(mlp_threads + 255) / 256, 256, 0, stream>>>(hid, W2, b2, phi);

    hist_kernel<<<(N_EDGES + 255) / 256, 256, 0, stream>>>(eidx, counts);
    scan_kernel<<<1, 1024, 0, stream>>>(counts, offsets, cursor);
    fill_kernel<<<(N_EDGES + 255) / 256, 256, 0, stream>>>(eidx, cursor, csr);

    gather_kernel<<<(N_NODES + 3) / 4, 256, 0, stream>>>(
        s, v, phi, radial, f_cut, unit, eidx, Wr, br,
        offsets, cursor, csr, out_s, out_v);
}

// Round 3
// 761.706 us; speedup vs baseline: 13.9650x; 1.6157x over previous
//
#include <hip/hip_runtime.h>
#include <math.h>

#define N_NODES 50000
#define N_EDGES 800000
#define F 64
#define R 32
#define C3F 192   // 3*F

// ---------------------------------------------------------------------------
// Fused MLP: phi = silu(s @ W1 + b1) @ W2 + b2      (N x 192)
// Block = 256 threads = 32 nodes x 8 segs. hidden staged in LDS (pad 68
// so phase-B reads of 8 distinct nodes hit distinct banks).
// ---------------------------------------------------------------------------
__global__ __launch_bounds__(256) void mlp_kernel(
    const float* __restrict__ s, const float* __restrict__ W1,
    const float* __restrict__ b1, const float* __restrict__ W2,
    const float* __restrict__ b2, float* __restrict__ phi)
{
    __shared__ float hid_s[32][68];

    int n = threadIdx.x >> 3;          // 0..31 local node
    int seg = threadIdx.x & 7;         // 0..7
    int node = blockIdx.x * 32 + n;
    bool live = node < N_NODES;

    // ---- phase A: hidden[seg*8 .. seg*8+8) = silu(s_row @ W1 + b1)
    if (live) {
        float sv[F];
        const float4* srow = (const float4*)(s + (size_t)node * F);
#pragma unroll
        for (int q = 0; q < F / 4; q++) {
            float4 t = srow[q];
            sv[4*q+0] = t.x; sv[4*q+1] = t.y; sv[4*q+2] = t.z; sv[4*q+3] = t.w;
        }
        float acc[8];
#pragma unroll
        for (int q = 0; q < 8; q++) acc[q] = b1[seg * 8 + q];
#pragma unroll
        for (int k = 0; k < F; k++) {
            float sk = sv[k];
            const float4* w = (const float4*)(W1 + (size_t)k * F + seg * 8);
            float4 w0 = w[0], w1 = w[1];
            acc[0] += sk * w0.x; acc[1] += sk * w0.y;
            acc[2] += sk * w0.z; acc[3] += sk * w0.w;
            acc[4] += sk * w1.x; acc[5] += sk * w1.y;
            acc[6] += sk * w1.z; acc[7] += sk * w1.w;
        }
#pragma unroll
        for (int q = 0; q < 8; q++) {
            float a = acc[q];
            hid_s[n][seg * 8 + q] = a / (1.f + __expf(-a));   // silu
        }
    }
    __syncthreads();

    // ---- phase B: phi[seg*24 .. seg*24+24) = hidden_row @ W2 + b2
    if (!live) return;

    float hv[F];
#pragma unroll
    for (int q = 0; q < F / 4; q++) {
        hv[4*q+0] = hid_s[n][4*q+0];
        hv[4*q+1] = hid_s[n][4*q+1];
        hv[4*q+2] = hid_s[n][4*q+2];
        hv[4*q+3] = hid_s[n][4*q+3];
    }

    float acc[24];
#pragma unroll
    for (int q = 0; q < 24; q++) acc[q] = b2[seg * 24 + q];
#pragma unroll
    for (int k = 0; k < F; k++) {
        float hk = hv[k];
        const float4* w = (const float4*)(W2 + (size_t)k * C3F + seg * 24);
#pragma unroll
        for (int q4 = 0; q4 < 6; q4++) {
            float4 wv = w[q4];
            acc[q4*4+0] += hk * wv.x;
            acc[q4*4+1] += hk * wv.y;
            acc[q4*4+2] += hk * wv.z;
            acc[q4*4+3] += hk * wv.w;
        }
    }
    float4* o = (float4*)(phi + (size_t)node * C3F + seg * 24);
#pragma unroll
    for (int q4 = 0; q4 < 6; q4++)
        o[q4] = make_float4(acc[q4*4+0], acc[q4*4+1], acc[q4*4+2], acc[q4*4+3]);
}

// ---------------------------------------------------------------------------
// CSR build: histogram -> unordered range alloc -> fill.
// Ranges need only be DISJOINT, not node-ordered, so a single atomic bump
// allocator replaces the ordered scan.
// ---------------------------------------------------------------------------
__global__ __launch_bounds__(256) void hist_kernel(
    const int* __restrict__ eidx, int* __restrict__ counts)
{
    int e = blockIdx.x * 256 + threadIdx.x;
    if (e < N_EDGES) atomicAdd(&counts[eidx[e]], 1);
}

__global__ __launch_bounds__(256) void alloc_kernel(
    const int* __restrict__ counts, int* __restrict__ total,
    int* __restrict__ offsets, int* __restrict__ cursor)
{
    int node = blockIdx.x * 256 + threadIdx.x;
    if (node < N_NODES) {
        int c = counts[node];
        int base = atomicAdd(total, c);
        offsets[node] = base;
        cursor[node]  = base;
    }
}

__global__ __launch_bounds__(256) void fill_kernel(
    const int* __restrict__ eidx, int* __restrict__ cursor,
    int* __restrict__ csr)
{
    int e = blockIdx.x * 256 + threadIdx.x;
    if (e < N_EDGES) {
        int pos = atomicAdd(&cursor[eidx[e]], 1);
        csr[pos] = e;
    }
}

// ---------------------------------------------------------------------------
// Gather kernel: one wave per node, lane = feature. node is readfirstlane'd
// so the whole csr->e->eidx/f_cut/unit/radial chain is provably uniform ->
// s_load (scalar cache), and the 96-FMA filter runs with SGPR broadcast
// operands (no shuffles, no LDS). Only phi/v rows are vector loads; those
// are software-pipelined one edge ahead to hide LLC latency.
// After fill_kernel, cursor[i] == row end.
// ---------------------------------------------------------------------------
__global__ __launch_bounds__(256) void gather_kernel(
    const float* __restrict__ s, const float* __restrict__ v,
    const float* __restrict__ phi, const float* __restrict__ radial,
    const float* __restrict__ f_cut, const float* __restrict__ unit_vec,
    const int* __restrict__ eidx, const float* __restrict__ Wr,
    const float* __restrict__ br, const int* __restrict__ offsets,
    const int* __restrict__ ends, const int* __restrict__ csr,
    float* __restrict__ out_s, float* __restrict__ out_v)
{
    int lane = threadIdx.x & 63;
    int node = __builtin_amdgcn_readfirstlane(
        (int)blockIdx.x * 4 + (int)(threadIdx.x >> 6));
    if (node >= N_NODES) return;

    // lane's 3 Wr columns (s, vv, vs) -> 96 VGPRs. Wr is 24 KB, cache-hot.
    float wr_s[R], wr_vv[R], wr_vs[R];
#pragma unroll
    for (int r = 0; r < R; r++) {
        const float* wrow = Wr + r * C3F;
        wr_s[r]  = wrow[lane];
        wr_vv[r] = wrow[64 + lane];
        wr_vs[r] = wrow[128 + lane];
    }
    float b_s = br[lane], b_vv = br[64 + lane], b_vs = br[128 + lane];

    float acc_s = 0.f, acc_v0 = 0.f, acc_v1 = 0.f, acc_v2 = 0.f;

    int k0 = __builtin_amdgcn_readfirstlane(offsets[node]);
    int k1 = __builtin_amdgcn_readfirstlane(ends[node]);

    if (k1 > k0) {
        // prologue: edge k0's indices + rows
        int e = __builtin_amdgcn_readfirstlane(csr[k0]);
        int j = __builtin_amdgcn_readfirstlane(eidx[N_EDGES + e]);
        const float* phij = phi + (size_t)j * C3F;
        const float* vjp  = v   + (size_t)j * C3F;
        float p_s  = phij[lane];
        float p_vv = phij[64 + lane];
        float p_vs = phij[128 + lane];
        float vr0  = vjp[lane];
        float vr1  = vjp[64 + lane];
        float vr2  = vjp[128 + lane];

        for (int k = k0; k < k1; k++) {
            // scalars for current edge (address known since last iter -> s_load
            // issues at loop top, wait overlaps with prefetch issue below)
            float fc = f_cut[e];
            float u0 = unit_vec[e * 3 + 0];
            float u1 = unit_vec[e * 3 + 1];
            float u2 = unit_vec[e * 3 + 2];
            const float* rp = radial + (size_t)e * R;

            // prefetch next edge's indices + rows
            int e_n = e, j_n = j;
            if (k + 1 < k1) {
                e_n = __builtin_amdgcn_readfirstlane(csr[k + 1]);
                j_n = __builtin_amdgcn_readfirstlane(eidx[N_EDGES + e_n]);
            }
            const float* phin = phi + (size_t)j_n * C3F;
            const float* vnp  = v   + (size_t)j_n * C3F;
            float np_s  = phin[lane];
            float np_vv = phin[64 + lane];
            float np_vs = phin[128 + lane];
            float nv0   = vnp[lane];
            float nv1   = vnp[64 + lane];
            float nv2   = vnp[128 + lane];

            // filter: W = radial_e @ Wr + br  (SGPR-broadcast FMAs)
            float ws = b_s, wvv = b_vv, wvs = b_vs;
#pragma unroll
            for (int r = 0; r < R; r++) {
                float rr = rp[r];
                ws  += rr * wr_s[r];
                wvv += rr * wr_vv[r];
                wvs += rr * wr_vs[r];
            }

            float xs  = p_s  * ws  * fc;
            float xvv = p_vv * wvv * fc;
            float xvs = p_vs * wvs * fc;
            acc_s  += xs;
            acc_v0 += vr0 * xvv + xvs * u0;
            acc_v1 += vr1 * xvv + xvs * u1;
            acc_v2 += vr2 * xvv + xvs * u2;

            // rotate pipeline
            e = e_n; j = j_n;
            p_s = np_s; p_vv = np_vv; p_vs = np_vs;
            vr0 = nv0; vr1 = nv1; vr2 = nv2;
        }
    }

    out_s[(size_t)node * F + lane] = s[(size_t)node * F + lane] + acc_s;
    const float* vi = v + (size_t)node * C3F;
    float* ovi = out_v + (size_t)node * C3F;
    ovi[lane]       = vi[lane]       + acc_v0;
    ovi[64 + lane]  = vi[64 + lane]  + acc_v1;
    ovi[128 + lane] = vi[128 + lane] + acc_v2;
}

// ---------------------------------------------------------------------------
extern "C" void kernel_launch(void* const* d_in, const int* in_sizes, int n_in,
                              void* d_out, int out_size, void* d_ws, size_t ws_size,
                              hipStream_t stream)
{
    const float* s      = (const float*)d_in[0];
    const float* v      = (const float*)d_in[1];
    const float* radial = (const float*)d_in[2];
    const float* f_cut  = (const float*)d_in[3];
    const float* unit   = (const float*)d_in[4];
    const int*   eidx   = (const int*)  d_in[5];
    const float* W1     = (const float*)d_in[6];
    const float* b1     = (const float*)d_in[7];
    const float* W2     = (const float*)d_in[8];
    const float* b2     = (const float*)d_in[9];
    const float* Wr     = (const float*)d_in[10];
    const float* br     = (const float*)d_in[11];

    float* out   = (float*)d_out;
    float* out_s = out;
    float* out_v = out + (size_t)N_NODES * F;

    // workspace layout
    float* phi     = (float*)d_ws;                         // 50000*192 f32
    int*   counts  = (int*)(phi + (size_t)N_NODES * C3F);  // 50000
    int*   total   = counts + N_NODES;                     // 1
    int*   offsets = total + 1;                            // 50000
    int*   cursor  = offsets + N_NODES;                    // 50000
    int*   csr     = cursor + N_NODES;                     // 800000
    // ~42 MB total

    hipMemsetAsync(counts, 0, (N_NODES + 1) * sizeof(int), stream);

    mlp_kernel<<<(N_NODES + 31) / 32, 256, 0, stream>>>(s, W1, b1, W2, b2, phi);

    hist_kernel<<<(N_EDGES + 255) / 256, 256, 0, stream>>>(eidx, counts);
    alloc_kernel<<<(N_NODES + 255) / 256, 256, 0, stream>>>(counts, total, offsets, cursor);
    fill_kernel<<<(N_EDGES + 255) / 256, 256, 0, stream>>>(eidx, cursor, csr);

    gather_kernel<<<(N_NODES + 3) / 4, 256, 0, stream>>>(
        s, v, phi, radial, f_cut, unit, eidx, Wr, br,
        offsets, cursor, csr, out_s, out_v);
}